// Round 12
// baseline (136.445 us; speedup 1.0000x reference)
//
#include <hip/hip_runtime.h>
#include <hip/hip_bf16.h>
#include <stdint.h>

// Problem constants
#define B_ 32
#define L_ 512
#define I_ 1024
#define O_ 1024
#define NST 32            // K-steps of BK=32

typedef float  f32x4 __attribute__((ext_vector_type(4)));
typedef float  f32x2 __attribute__((ext_vector_type(2)));
typedef __bf16 bf16x4 __attribute__((ext_vector_type(4)));
typedef __bf16 bf16x8 __attribute__((ext_vector_type(8)));

#define CFENCE() asm volatile("" ::: "memory")
#define BARRIER() do { CFENCE(); __builtin_amdgcn_s_barrier(); CFENCE(); } while (0)
#define LGKM0()  asm volatile("s_waitcnt lgkmcnt(0)" ::: "memory")

// ============================ Pass 0: mean,logvar f32 -> mean bf16, sigma bf16 (4 MiB) ============================
__global__ void gen_ms_kernel(const float* __restrict__ wmean, const float* __restrict__ wlv,
                              __bf16* __restrict__ mz, __bf16* __restrict__ sgm)
{
    const int i = blockIdx.x * blockDim.x + threadIdx.x;   // exactly O*I/4 threads
    const f32x4 m = *(const f32x4*)(wmean + (size_t)i * 4);
    const f32x4 l = *(const f32x4*)(wlv   + (size_t)i * 4);
    bf16x4 mb, sb;
    #pragma unroll
    for (int e = 0; e < 4; ++e) {
        mb[e] = (__bf16)m[e];
        sb[e] = (__bf16)__expf(0.5f * l[e]);
    }
    *(bf16x4*)(mz  + (size_t)i * 4) = mb;
    *(bf16x4*)(sgm + (size_t)i * 4) = sb;
}

// ============================ Fused 128x128 GEMM, TLP-first design ============================
// C[b](512x1024) = X[b] * (mean + noise[b]*sigma)^T + bias.
// 512 thr = 8 waves (4M x 2N), per-wave 32x64 out = 2m x 4n frags -> acc only 32 regs.
// LDS 40 KB: 2 dbuf x (A 128x[32k] + B 128x[32k]) bf16, rows PADDED to 80 B
// (stride 5 chunks -> frag-read bank quads spread over all 8, 2-way = free; no swizzle).
// Reg-staged fused staging: per step issue loads(t+2) / transform+write(t+1) / MFMA(t),
// ONE raw s_barrier per step (global prefetch vmcnt rides across; lgkmcnt(0) for write vis).
// __launch_bounds__(512,4): force <=128 unified regs -> 2 blocks/CU = 16 waves/CU.
__global__ __launch_bounds__(512, 4) void fused_gemm(const float* __restrict__ x,
                                                     const float* __restrict__ noise,
                                                     const __bf16* __restrict__ mz,
                                                     const __bf16* __restrict__ sgm,
                                                     const float* __restrict__ bias,
                                                     float* __restrict__ out)
{
    __shared__ __align__(16) char smem[40960];
    // buf d at d*20480: A rows 128 x 80B (10240 B), then B rows 128 x 80B.

    // XCD swizzle (1024 % 8 == 0): 128 consecutive logical blocks per XCD = 4 whole batches.
    // Logical: batch-major, mt then nt fastest (8 nt-blocks sharing an x-slice co-dispatch).
    const int bid = ((int)blockIdx.x & 7) * 128 + ((int)blockIdx.x >> 3);
    const int b   = bid >> 5;
    const int mt  = (bid >> 3) & 3;    // 4 M-tiles of 128
    const int nt  = bid & 7;           // 8 N-tiles of 128

    const int tid  = threadIdx.x;      // 0..511
    const int wid  = tid >> 6, lane = tid & 63;
    const int wr   = wid >> 1;         // 0..3 (M, 32-row slabs)
    const int wc   = wid & 1;          // 0..1 (N, 64-col halves)
    const int hr   = lane & 15;
    const int kq   = lane >> 4;        // 0..3

    // ---- staging geometry: thread owns chunk tid: row=tid>>2 (0..127), kc=tid&3 (8 bf16 / 4+4 f32) ----
    const int rS = tid >> 2, kc = tid & 3;
    const float*  xg = x     + ((size_t)b * L_ + mt * 128 + rS) * I_ + kc * 8;
    const float*  ng = noise + ((size_t)b * O_ + nt * 128 + rS) * I_ + kc * 8;
    const __bf16* mg = mz    + (size_t)(nt * 128 + rS) * I_ + kc * 8;
    const __bf16* gg = sgm   + (size_t)(nt * 128 + rS) * I_ + kc * 8;
    const int wbyte = rS * 80 + kc * 16;          // padded-row LDS write byte (A); B = +10240

    // ---- staged registers (live across one step) ----
    f32x4 sa0, sa1, sn0, sn1; bf16x8 sm, ss;

#define ISSUE(k0_) do {                                       \
        sa0 = *(const f32x4*)(xg + (k0_));                    \
        sa1 = *(const f32x4*)(xg + (k0_) + 4);                \
        sn0 = *(const f32x4*)(ng + (k0_));                    \
        sn1 = *(const f32x4*)(ng + (k0_) + 4);                \
        sm  = *(const bf16x8*)(mg + (k0_));                   \
        ss  = *(const bf16x8*)(gg + (k0_));                   \
    } while (0)

#define TW(d_) do {                                                        \
        bf16x8 aw_, ww_;                                                   \
        _Pragma("unroll")                                                  \
        for (int e = 0; e < 4; ++e) {                                      \
            aw_[e]   = (__bf16)sa0[e];                                     \
            aw_[e+4] = (__bf16)sa1[e];                                     \
            ww_[e]   = (__bf16)((float)sm[e]   + sn0[e] * (float)ss[e]);   \
            ww_[e+4] = (__bf16)((float)sm[e+4] + sn1[e] * (float)ss[e+4]); \
        }                                                                  \
        *(bf16x8*)(smem + (d_) * 20480 + wbyte)         = aw_;             \
        *(bf16x8*)(smem + (d_) * 20480 + 10240 + wbyte) = ww_;             \
    } while (0)

    // ---- frag read byte offsets (padded rows: stride 80, logical k-chunk = kq, no swizzle) ----
    const int aoff0 = (wr * 32 + 0 * 16 + hr) * 80 + kq * 16;
    const int aoff1 = (wr * 32 + 1 * 16 + hr) * 80 + kq * 16;
    int boff[4];
    #pragma unroll
    for (int nf = 0; nf < 4; ++nf)
        boff[nf] = 10240 + (wc * 64 + nf * 16 + hr) * 80 + kq * 16;

    f32x4 acc[2][4];
    #pragma unroll
    for (int m = 0; m < 2; ++m)
        #pragma unroll
        for (int n = 0; n < 4; ++n)
            acc[m][n] = (f32x4)(0.0f);

    // ---- prologue: build tile 0, issue tile 1 ----
    ISSUE(0);
    TW(0);                 // compiler inserts vmcnt wait for staged regs
    ISSUE(32);
    LGKM0();
    BARRIER();

    for (int t = 0; t < NST; ++t) {
        const int d = t & 1;
        const char* base = smem + d * 20480;

        bf16x8 af0 = *(const bf16x8*)(base + aoff0);
        bf16x8 af1 = *(const bf16x8*)(base + aoff1);
        bf16x8 bf[4];
        #pragma unroll
        for (int nf = 0; nf < 4; ++nf)
            bf[nf] = *(const bf16x8*)(base + boff[nf]);

        __builtin_amdgcn_s_setprio(1);
        #pragma unroll
        for (int nf = 0; nf < 4; ++nf) {
            acc[0][nf] = __builtin_amdgcn_mfma_f32_16x16x32_bf16(af0, bf[nf], acc[0][nf], 0, 0, 0);
            acc[1][nf] = __builtin_amdgcn_mfma_f32_16x16x32_bf16(af1, bf[nf], acc[1][nf], 0, 0, 0);
        }
        __builtin_amdgcn_s_setprio(0);

        if (t + 1 < NST) TW(d ^ 1);             // transform regs of tile t+1, write other buf
        if (t + 2 < NST) ISSUE((t + 2) * 32);   // prefetch tile t+2 (vmcnt crosses barrier)
        LGKM0();                                 // ds_writes visible before barrier
        BARRIER();
    }
#undef ISSUE
#undef TW

    // ---- epilogue: LDS transpose -> coalesced stores (512B/wave-instr) ----
    {
        float* eb = (float*)smem;               // [64][130] f32 per round (33.3 KB)
        const f32x2 bias2 = *(const f32x2*)(bias + nt * 128 + lane * 2);
        float* ob = out + ((size_t)b * L_ + mt * 128) * O_ + nt * 128;
        #pragma unroll
        for (int r = 0; r < 2; ++r) {
            BARRIER();                           // prior LDS use done
            if ((wr >> 1) == r) {
                #pragma unroll
                for (int mf = 0; mf < 2; ++mf)
                    #pragma unroll
                    for (int nf = 0; nf < 4; ++nf) {
                        const int col = wc * 64 + nf * 16 + hr;
                        #pragma unroll
                        for (int j = 0; j < 4; ++j)
                            eb[((wr & 1) * 32 + mf * 16 + kq * 4 + j) * 130 + col] = acc[mf][nf][j];
                    }
            }
            BARRIER();                           // publish slab
            #pragma unroll
            for (int rr = 0; rr < 8; ++rr) {
                const int row = wid * 8 + rr;    // 0..63
                f32x2 v = *(const f32x2*)&eb[row * 130 + lane * 2];
                v[0] += bias2[0]; v[1] += bias2[1];
                *(f32x2*)&ob[(size_t)(r * 64 + row) * O_ + lane * 2] = v;
            }
        }
    }
}

// ============================ Fallback (no workspace): R1 fused kernel ============================
#define LDSPAD 40
__global__ void bayes_gemm_fused(const float* __restrict__ x,
                                 const float* __restrict__ wmean,
                                 const float* __restrict__ wlogvar,
                                 const float* __restrict__ bias,
                                 const float* __restrict__ noise,
                                 float* __restrict__ out)
{
    __shared__ __bf16 As[128 * LDSPAD];
    __shared__ __bf16 Bs[128 * LDSPAD];
    const int bid  = blockIdx.x;
    const int b    = bid >> 5;
    const int mt   = (bid >> 3) & 3;
    const int nt   = bid & 7;
    const int t    = threadIdx.x;
    const int wave = t >> 6, lane = t & 63;
    const int wr   = wave >> 1, wc = wave & 1;
    const int hr   = lane & 15, kq = lane >> 4;
    const float* xb = x     + (size_t)b * L_ * I_;
    const float* nb = noise + (size_t)b * O_ * I_;
    f32x4 acc[4][4];
    #pragma unroll
    for (int m = 0; m < 4; ++m)
        #pragma unroll
        for (int n = 0; n < 4; ++n) acc[m][n] = (f32x4)(0.0f);
    for (int k0 = 0; k0 < I_; k0 += 32) {
        #pragma unroll
        for (int j = 0; j < 4; ++j) {
            const int s = t + j * 256, row = s >> 3, q = s & 7;
            const float4 v = *(const float4*)(xb + (size_t)(mt * 128 + row) * I_ + k0 + q * 4);
            __bf16* dst = &As[row * LDSPAD + q * 4];
            dst[0] = (__bf16)v.x; dst[1] = (__bf16)v.y; dst[2] = (__bf16)v.z; dst[3] = (__bf16)v.w;
        }
        #pragma unroll
        for (int j = 0; j < 4; ++j) {
            const int s = t + j * 256, row = s >> 3, q = s & 7;
            const size_t off = (size_t)(nt * 128 + row) * I_ + k0 + q * 4;
            const float4 m4 = *(const float4*)(wmean + off);
            const float4 l4 = *(const float4*)(wlogvar + off);
            const float4 n4 = *(const float4*)(nb + off);
            __bf16* dst = &Bs[row * LDSPAD + q * 4];
            dst[0] = (__bf16)(m4.x + n4.x * __expf(0.5f * l4.x));
            dst[1] = (__bf16)(m4.y + n4.y * __expf(0.5f * l4.y));
            dst[2] = (__bf16)(m4.z + n4.z * __expf(0.5f * l4.z));
            dst[3] = (__bf16)(m4.w + n4.w * __expf(0.5f * l4.w));
        }
        __syncthreads();
        bf16x8 af[4], bfr[4];
        #pragma unroll
        for (int m = 0; m < 4; ++m)
            af[m] = *(const bf16x8*)&As[(wr * 64 + m * 16 + hr) * LDSPAD + kq * 8];
        #pragma unroll
        for (int n = 0; n < 4; ++n)
            bfr[n] = *(const bf16x8*)&Bs[(wc * 64 + n * 16 + hr) * LDSPAD + kq * 8];
        #pragma unroll
        for (int m = 0; m < 4; ++m)
            #pragma unroll
            for (int n = 0; n < 4; ++n)
                acc[m][n] = __builtin_amdgcn_mfma_f32_16x16x32_bf16(af[m], bfr[n], acc[m][n], 0, 0, 0);
        __syncthreads();
    }
    float* ob = out + (size_t)b * L_ * O_;
    #pragma unroll
    for (int n = 0; n < 4; ++n) {
        const int col = nt * 128 + wc * 64 + n * 16 + hr;
        const float bv = bias[col];
        #pragma unroll
        for (int m = 0; m < 4; ++m) {
            const int row0 = mt * 128 + wr * 64 + m * 16 + kq * 4;
            #pragma unroll
            for (int j = 0; j < 4; ++j)
                ob[(size_t)(row0 + j) * O_ + col] = acc[m][n][j] + bv;
        }
    }
}

extern "C" void kernel_launch(void* const* d_in, const int* in_sizes, int n_in,
                              void* d_out, int out_size, void* d_ws, size_t ws_size,
                              hipStream_t stream) {
    const float* x       = (const float*)d_in[0];
    const float* wmean   = (const float*)d_in[1];
    const float* wlogvar = (const float*)d_in[2];
    const float* bias    = (const float*)d_in[3];
    const float* noise   = (const float*)d_in[4];
    float* out           = (float*)d_out;

    const size_t ms_bytes = (size_t)O_ * I_ * 2 * 2;   // mean bf16 + sigma bf16 = 4 MiB

    if (ws_size >= ms_bytes) {
        __bf16* mzb = (__bf16*)d_ws;
        __bf16* sgb = mzb + (size_t)O_ * I_;
        gen_ms_kernel<<<dim3(O_ * I_ / 4 / 256), dim3(256), 0, stream>>>(wmean, wlogvar, mzb, sgb);
        fused_gemm<<<dim3(1024), dim3(512), 0, stream>>>(x, noise, mzb, sgb, bias, out);
    } else {
        bayes_gemm_fused<<<dim3(1024), dim3(256), 0, stream>>>(
            x, wmean, wlogvar, bias, noise, out);
    }
}

// Round 13
// 118.372 us; speedup vs baseline: 1.1527x; 1.1527x over previous
//
#include <hip/hip_runtime.h>
#include <hip/hip_bf16.h>
#include <stdint.h>

// Problem constants
#define B_ 32
#define L_ 512
#define I_ 1024
#define O_ 1024
#define NST 32            // K-steps of BK=32

typedef float  f32x4 __attribute__((ext_vector_type(4)));
typedef float  f32x2 __attribute__((ext_vector_type(2)));
typedef __bf16 bf16x4 __attribute__((ext_vector_type(4)));
typedef __bf16 bf16x8 __attribute__((ext_vector_type(8)));

#define CFENCE() asm volatile("" ::: "memory")
#define BARRIER() do { CFENCE(); __builtin_amdgcn_s_barrier(); CFENCE(); } while (0)
#define LGKM0()  asm volatile("s_waitcnt lgkmcnt(0)" ::: "memory")

// ============================ Pass 0: mean,logvar f32 -> mean bf16, sigma bf16 (4 MiB) ============================
__global__ void gen_ms_kernel(const float* __restrict__ wmean, const float* __restrict__ wlv,
                              __bf16* __restrict__ mz, __bf16* __restrict__ sgm)
{
    const int i = blockIdx.x * blockDim.x + threadIdx.x;   // exactly O*I/4 threads
    const f32x4 m = *(const f32x4*)(wmean + (size_t)i * 4);
    const f32x4 l = *(const f32x4*)(wlv   + (size_t)i * 4);
    bf16x4 mb, sb;
    #pragma unroll
    for (int e = 0; e < 4; ++e) {
        mb[e] = (__bf16)m[e];
        sb[e] = (__bf16)__expf(0.5f * l[e]);
    }
    *(bf16x4*)(mz  + (size_t)i * 4) = mb;
    *(bf16x4*)(sgm + (size_t)i * 4) = sb;
}

// ============================ Fused 128x128 GEMM, 4-wave, 3 blocks/CU ============================
// C[b](512x1024) = X[b] * (mean + noise[b]*sigma)^T + bias.
// 256 thr = 4 waves (2M x 2N), per-wave 64x64 out = 4x4 frags -> acc 64 regs; staging ~48;
// __launch_bounds__(256,3): ~170-reg cap -> 3 blocks/CU = 12 waves/CU WITHOUT the R12
// register starvation (R12's (512,4) -> 52 regs serialized all staging loads: 175us).
// LDS 32 KB: 2 dbuf x [A 128x32 + B 128x32] bf16, LINEAR rows (frag reads alias exactly
// 2 lanes/bank-quad = free, m136; R12's 80B pad caused 1.1e7 conflict cycles).
// Pipeline: MFMA(t) | transform+ds_write(t+1) | issue loads(t+2); one lgkm+barrier/step;
// compiler auto-inserts counted vmcnt for the staged-reg deps (T14).
__global__ __launch_bounds__(256, 3) void fused_gemm(const float* __restrict__ x,
                                                     const float* __restrict__ noise,
                                                     const __bf16* __restrict__ mz,
                                                     const __bf16* __restrict__ sgm,
                                                     const float* __restrict__ bias,
                                                     float* __restrict__ out)
{
    __shared__ __align__(16) char smem[33280];
    // buf d at d*16384: A rows 128x64B, then B rows 128x64B. Epilogue: [64][130] f32.

    // XCD swizzle (1024 % 8 == 0): 128 consecutive logical blocks per XCD = 4 whole batches.
    const int bid = ((int)blockIdx.x & 7) * 128 + ((int)blockIdx.x >> 3);
    const int b   = bid >> 5;
    const int mt  = (bid >> 3) & 3;    // 4 M-tiles of 128
    const int nt  = bid & 7;           // 8 N-tiles of 128

    const int tid  = threadIdx.x;      // 0..255
    const int wave = tid >> 6, lane = tid & 63;
    const int wr   = wave >> 1;        // 0..1 (M halves)
    const int wc   = wave & 1;         // 0..1 (N halves)
    const int hr   = lane & 15;
    const int kq   = lane >> 4;        // 0..3

    // ---- staging geometry: thread owns chunks tid (row r1) and tid+256 (row r1+64), col kc*8 ----
    const int r1 = tid >> 2, kc = tid & 3;
    const float*  xg = x     + ((size_t)b * L_ + mt * 128 + r1) * I_ + kc * 8;
    const float*  ng = noise + ((size_t)b * O_ + nt * 128 + r1) * I_ + kc * 8;
    const __bf16* mg = mz    + (size_t)(nt * 128 + r1) * I_ + kc * 8;
    const __bf16* gg = sgm   + (size_t)(nt * 128 + r1) * I_ + kc * 8;
    const size_t H64 = (size_t)64 * I_;          // +64 rows
    const int wb = tid * 16;                     // LDS write byte (chunk1); chunk2 = +4096

    // ---- staged registers ----
    f32x4 sa0, sa1, sa2, sa3;      // x: chunk1 lo/hi, chunk2 lo/hi
    f32x4 sn0, sn1, sn2, sn3;      // noise
    bf16x8 sm0, sm1, sg0, sg1;     // mean, sigma

#define ISSUE(k0_) do {                                      \
        sa0 = *(const f32x4*)(xg + (k0_));                   \
        sa1 = *(const f32x4*)(xg + (k0_) + 4);               \
        sa2 = *(const f32x4*)(xg + (k0_) + H64);             \
        sa3 = *(const f32x4*)(xg + (k0_) + H64 + 4);         \
        sn0 = *(const f32x4*)(ng + (k0_));                   \
        sn1 = *(const f32x4*)(ng + (k0_) + 4);               \
        sn2 = *(const f32x4*)(ng + (k0_) + H64);             \
        sn3 = *(const f32x4*)(ng + (k0_) + H64 + 4);         \
        sm0 = *(const bf16x8*)(mg + (k0_));                  \
        sm1 = *(const bf16x8*)(mg + (k0_) + H64);            \
        sg0 = *(const bf16x8*)(gg + (k0_));                  \
        sg1 = *(const bf16x8*)(gg + (k0_) + H64);            \
    } while (0)

#define TW(d_) do {                                                         \
        bf16x8 a0_, a1_, w0_, w1_;                                          \
        _Pragma("unroll")                                                   \
        for (int e = 0; e < 4; ++e) {                                       \
            a0_[e]   = (__bf16)sa0[e];  a0_[e+4] = (__bf16)sa1[e];          \
            a1_[e]   = (__bf16)sa2[e];  a1_[e+4] = (__bf16)sa3[e];          \
            w0_[e]   = (__bf16)((float)sm0[e]   + sn0[e] * (float)sg0[e]);  \
            w0_[e+4] = (__bf16)((float)sm0[e+4] + sn1[e] * (float)sg0[e+4]);\
            w1_[e]   = (__bf16)((float)sm1[e]   + sn2[e] * (float)sg1[e]);  \
            w1_[e+4] = (__bf16)((float)sm1[e+4] + sn3[e] * (float)sg1[e+4]);\
        }                                                                   \
        *(bf16x8*)(smem + (d_) * 16384 + wb)               = a0_;           \
        *(bf16x8*)(smem + (d_) * 16384 + wb + 4096)        = a1_;           \
        *(bf16x8*)(smem + (d_) * 16384 + 8192 + wb)        = w0_;           \
        *(bf16x8*)(smem + (d_) * 16384 + 8192 + wb + 4096) = w1_;           \
    } while (0)

    // ---- frag read byte offsets (linear 64B rows; 2-way quad aliasing = free) ----
    int aoff[4], boff[4];
    #pragma unroll
    for (int f = 0; f < 4; ++f) {
        aoff[f] = (wr * 64 + f * 16 + hr) * 64 + kq * 16;
        boff[f] = 8192 + (wc * 64 + f * 16 + hr) * 64 + kq * 16;
    }

    f32x4 acc[4][4];
    #pragma unroll
    for (int m = 0; m < 4; ++m)
        #pragma unroll
        for (int n = 0; n < 4; ++n)
            acc[m][n] = (f32x4)(0.0f);

    // ---- prologue: build tile 0 into buf 0; issue tile 1 ----
    ISSUE(0);
    TW(0);                  // compiler waits vmcnt for staged regs
    ISSUE(32);
    LGKM0();
    BARRIER();

    for (int t = 0; t < NST; ++t) {
        const char* base = smem + (t & 1) * 16384;

        bf16x8 af[4], bfr[4];
        #pragma unroll
        for (int f = 0; f < 4; ++f) {
            af[f]  = *(const bf16x8*)(base + aoff[f]);
            bfr[f] = *(const bf16x8*)(base + boff[f]);
        }

        __builtin_amdgcn_s_setprio(1);
        #pragma unroll
        for (int m = 0; m < 4; ++m)
            #pragma unroll
            for (int n = 0; n < 4; ++n)
                acc[m][n] = __builtin_amdgcn_mfma_f32_16x16x32_bf16(af[m], bfr[n], acc[m][n], 0, 0, 0);
        __builtin_amdgcn_s_setprio(0);

        if (t + 1 < NST) TW((t + 1) & 1);          // transform tile t+1, write other buf
        if (t + 2 < NST) ISSUE((t + 2) * 32);      // prefetch tile t+2
        LGKM0();                                   // ds_writes visible to all waves
        BARRIER();
    }
#undef ISSUE
#undef TW

    // ---- epilogue: LDS transpose -> coalesced stores (512B contiguous per wave-instr) ----
    {
        float* eb = (float*)smem;                  // [64][130] f32 per round
        const f32x2 bias2 = *(const f32x2*)(bias + nt * 128 + lane * 2);
        float* ob = out + ((size_t)b * L_ + mt * 128) * O_ + nt * 128;
        #pragma unroll
        for (int r = 0; r < 2; ++r) {
            BARRIER();                             // prior LDS use done
            if (wr == r) {
                #pragma unroll
                for (int m = 0; m < 4; ++m)
                    #pragma unroll
                    for (int n = 0; n < 4; ++n) {
                        const int col = wc * 64 + n * 16 + hr;
                        #pragma unroll
                        for (int j = 0; j < 4; ++j)
                            eb[(m * 16 + kq * 4 + j) * 130 + col] = acc[m][n][j];
                    }
            }
            BARRIER();                             // publish slab
            #pragma unroll
            for (int rr = 0; rr < 16; ++rr) {
                const int row = wave * 16 + rr;    // 0..63
                f32x2 v = *(const f32x2*)&eb[row * 130 + lane * 2];
                v[0] += bias2[0]; v[1] += bias2[1];
                *(f32x2*)&ob[(size_t)(r * 64 + row) * O_ + lane * 2] = v;
            }
        }
    }
}

// ============================ Fallback (no workspace): R1 fused kernel ============================
#define LDSPAD 40
__global__ void bayes_gemm_fused(const float* __restrict__ x,
                                 const float* __restrict__ wmean,
                                 const float* __restrict__ wlogvar,
                                 const float* __restrict__ bias,
                                 const float* __restrict__ noise,
                                 float* __restrict__ out)
{
    __shared__ __bf16 As[128 * LDSPAD];
    __shared__ __bf16 Bs[128 * LDSPAD];
    const int bid  = blockIdx.x;
    const int b    = bid >> 5;
    const int mt   = (bid >> 3) & 3;
    const int nt   = bid & 7;
    const int t    = threadIdx.x;
    const int wave = t >> 6, lane = t & 63;
    const int wr   = wave >> 1, wc = wave & 1;
    const int hr   = lane & 15, kq = lane >> 4;
    const float* xb = x     + (size_t)b * L_ * I_;
    const float* nb = noise + (size_t)b * O_ * I_;
    f32x4 acc[4][4];
    #pragma unroll
    for (int m = 0; m < 4; ++m)
        #pragma unroll
        for (int n = 0; n < 4; ++n) acc[m][n] = (f32x4)(0.0f);
    for (int k0 = 0; k0 < I_; k0 += 32) {
        #pragma unroll
        for (int j = 0; j < 4; ++j) {
            const int s = t + j * 256, row = s >> 3, q = s & 7;
            const float4 v = *(const float4*)(xb + (size_t)(mt * 128 + row) * I_ + k0 + q * 4);
            __bf16* dst = &As[row * LDSPAD + q * 4];
            dst[0] = (__bf16)v.x; dst[1] = (__bf16)v.y; dst[2] = (__bf16)v.z; dst[3] = (__bf16)v.w;
        }
        #pragma unroll
        for (int j = 0; j < 4; ++j) {
            const int s = t + j * 256, row = s >> 3, q = s & 7;
            const size_t off = (size_t)(nt * 128 + row) * I_ + k0 + q * 4;
            const float4 m4 = *(const float4*)(wmean + off);
            const float4 l4 = *(const float4*)(wlogvar + off);
            const float4 n4 = *(const float4*)(nb + off);
            __bf16* dst = &Bs[row * LDSPAD + q * 4];
            dst[0] = (__bf16)(m4.x + n4.x * __expf(0.5f * l4.x));
            dst[1] = (__bf16)(m4.y + n4.y * __expf(0.5f * l4.y));
            dst[2] = (__bf16)(m4.z + n4.z * __expf(0.5f * l4.z));
            dst[3] = (__bf16)(m4.w + n4.w * __expf(0.5f * l4.w));
        }
        __syncthreads();
        bf16x8 af[4], bfr[4];
        #pragma unroll
        for (int m = 0; m < 4; ++m)
            af[m] = *(const bf16x8*)&As[(wr * 64 + m * 16 + hr) * LDSPAD + kq * 8];
        #pragma unroll
        for (int n = 0; n < 4; ++n)
            bfr[n] = *(const bf16x8*)&Bs[(wc * 64 + n * 16 + hr) * LDSPAD + kq * 8];
        #pragma unroll
        for (int m = 0; m < 4; ++m)
            #pragma unroll
            for (int n = 0; n < 4; ++n)
                acc[m][n] = __builtin_amdgcn_mfma_f32_16x16x32_bf16(af[m], bfr[n], acc[m][n], 0, 0, 0);
        __syncthreads();
    }
    float* ob = out + (size_t)b * L_ * O_;
    #pragma unroll
    for (int n = 0; n < 4; ++n) {
        const int col = nt * 128 + wc * 64 + n * 16 + hr;
        const float bv = bias[col];
        #pragma unroll
        for (int m = 0; m < 4; ++m) {
            const int row0 = mt * 128 + wr * 64 + m * 16 + kq * 4;
            #pragma unroll
            for (int j = 0; j < 4; ++j)
                ob[(size_t)(row0 + j) * O_ + col] = acc[m][n][j] + bv;
        }
    }
}

extern "C" void kernel_launch(void* const* d_in, const int* in_sizes, int n_in,
                              void* d_out, int out_size, void* d_ws, size_t ws_size,
                              hipStream_t stream) {
    const float* x       = (const float*)d_in[0];
    const float* wmean   = (const float*)d_in[1];
    const float* wlogvar = (const float*)d_in[2];
    const float* bias    = (const float*)d_in[3];
    const float* noise   = (const float*)d_in[4];
    float* out           = (float*)d_out;

    const size_t ms_bytes = (size_t)O_ * I_ * 2 * 2;   // mean bf16 + sigma bf16 = 4 MiB

    if (ws_size >= ms_bytes) {
        __bf16* mzb = (__bf16*)d_ws;
        __bf16* sgb = mzb + (size_t)O_ * I_;
        gen_ms_kernel<<<dim3(O_ * I_ / 4 / 256), dim3(256), 0, stream>>>(wmean, wlogvar, mzb, sgb);
        fused_gemm<<<dim3(1024), dim3(256), 0, stream>>>(x, noise, mzb, sgb, bias, out);
    } else {
        bayes_gemm_fused<<<dim3(1024), dim3(256), 0, stream>>>(
            x, wmean, wlogvar, bias, noise, out);
    }
}

// Round 15
// 116.677 us; speedup vs baseline: 1.1694x; 1.0145x over previous
//
#include <hip/hip_runtime.h>
#include <hip/hip_bf16.h>
#include <stdint.h>

// Problem constants
#define B_ 32
#define L_ 512
#define I_ 1024
#define O_ 1024
#define NST 32            // K-steps of BK=32

typedef float  f32x4 __attribute__((ext_vector_type(4)));
typedef float  f32x2 __attribute__((ext_vector_type(2)));
typedef __bf16 bf16x4 __attribute__((ext_vector_type(4)));
typedef __bf16 bf16x8 __attribute__((ext_vector_type(8)));

#define CFENCE() asm volatile("" ::: "memory")
#define BARRIER() do { CFENCE(); __builtin_amdgcn_s_barrier(); CFENCE(); } while (0)
#define LGKM0()  asm volatile("s_waitcnt lgkmcnt(0)" ::: "memory")

// ============================ Pass 0: mean,logvar f32 -> mean bf16, sigma bf16 (4 MiB) ============================
__global__ void gen_ms_kernel(const float* __restrict__ wmean, const float* __restrict__ wlv,
                              __bf16* __restrict__ mz, __bf16* __restrict__ sgm)
{
    const int i = blockIdx.x * blockDim.x + threadIdx.x;   // exactly O*I/4 threads
    const f32x4 m = *(const f32x4*)(wmean + (size_t)i * 4);
    const f32x4 l = *(const f32x4*)(wlv   + (size_t)i * 4);
    bf16x4 mb, sb;
    #pragma unroll
    for (int e = 0; e < 4; ++e) {
        mb[e] = (__bf16)m[e];
        sb[e] = (__bf16)__expf(0.5f * l[e]);
    }
    *(bf16x4*)(mz  + (size_t)i * 4) = mb;
    *(bf16x4*)(sgm + (size_t)i * 4) = sb;
}

// ============================ Fused 128x128 GEMM, 4-wave ============================
// R15 = R13 (passed, 145us) with ONE change: __launch_bounds__(256, 2) instead of (256, 3).
// Diagnosis: the min-waves-per-EU=3 hint made the scheduler TARGET that occupancy by
// minimizing registers (VGPR 84; R12's (512,4) -> 52): it sank the 12 staging loads to
// their uses, serializing the memory pipeline. R11's (512,2) context produced 128 VGPR
// and pipelined codegen on the same fused math. (256,2) relaxes the target; ~128 VGPR
// + 33 KB LDS still admits 3-4 blocks/CU = 12-16 waves/CU.
__global__ __launch_bounds__(256, 2) void fused_gemm(const float* __restrict__ x,
                                                     const float* __restrict__ noise,
                                                     const __bf16* __restrict__ mz,
                                                     const __bf16* __restrict__ sgm,
                                                     const float* __restrict__ bias,
                                                     float* __restrict__ out)
{
    __shared__ __align__(16) char smem[33280];
    // buf d at d*16384: A rows 128x64B, then B rows 128x64B. Epilogue: [64][130] f32.

    // XCD swizzle (1024 % 8 == 0): 128 consecutive logical blocks per XCD = 4 whole batches.
    const int bid = ((int)blockIdx.x & 7) * 128 + ((int)blockIdx.x >> 3);
    const int b   = bid >> 5;
    const int mt  = (bid >> 3) & 3;    // 4 M-tiles of 128
    const int nt  = bid & 7;           // 8 N-tiles of 128

    const int tid  = threadIdx.x;      // 0..255
    const int wave = tid >> 6, lane = tid & 63;
    const int wr   = wave >> 1;        // 0..1 (M halves)
    const int wc   = wave & 1;         // 0..1 (N halves)
    const int hr   = lane & 15;
    const int kq   = lane >> 4;        // 0..3

    // ---- staging geometry: thread owns chunks tid (row r1) and tid+256 (row r1+64), col kc*8 ----
    const int r1 = tid >> 2, kc = tid & 3;
    const float*  xg = x     + ((size_t)b * L_ + mt * 128 + r1) * I_ + kc * 8;
    const float*  ng = noise + ((size_t)b * O_ + nt * 128 + r1) * I_ + kc * 8;
    const __bf16* mg = mz    + (size_t)(nt * 128 + r1) * I_ + kc * 8;
    const __bf16* gg = sgm   + (size_t)(nt * 128 + r1) * I_ + kc * 8;
    const size_t H64 = (size_t)64 * I_;          // +64 rows
    const int wb = tid * 16;                     // LDS write byte (chunk1); chunk2 = +4096

    // ---- staged registers ----
    f32x4 sa0, sa1, sa2, sa3;      // x: chunk1 lo/hi, chunk2 lo/hi
    f32x4 sn0, sn1, sn2, sn3;      // noise
    bf16x8 sm0, sm1, sg0, sg1;     // mean, sigma

#define ISSUE(k0_) do {                                      \
        sa0 = *(const f32x4*)(xg + (k0_));                   \
        sa1 = *(const f32x4*)(xg + (k0_) + 4);               \
        sa2 = *(const f32x4*)(xg + (k0_) + H64);             \
        sa3 = *(const f32x4*)(xg + (k0_) + H64 + 4);         \
        sn0 = *(const f32x4*)(ng + (k0_));                   \
        sn1 = *(const f32x4*)(ng + (k0_) + 4);               \
        sn2 = *(const f32x4*)(ng + (k0_) + H64);             \
        sn3 = *(const f32x4*)(ng + (k0_) + H64 + 4);         \
        sm0 = *(const bf16x8*)(mg + (k0_));                  \
        sm1 = *(const bf16x8*)(mg + (k0_) + H64);            \
        sg0 = *(const bf16x8*)(gg + (k0_));                  \
        sg1 = *(const bf16x8*)(gg + (k0_) + H64);            \
    } while (0)

#define TW(d_) do {                                                         \
        bf16x8 a0_, a1_, w0_, w1_;                                          \
        _Pragma("unroll")                                                   \
        for (int e = 0; e < 4; ++e) {                                       \
            a0_[e]   = (__bf16)sa0[e];  a0_[e+4] = (__bf16)sa1[e];          \
            a1_[e]   = (__bf16)sa2[e];  a1_[e+4] = (__bf16)sa3[e];          \
            w0_[e]   = (__bf16)((float)sm0[e]   + sn0[e] * (float)sg0[e]);  \
            w0_[e+4] = (__bf16)((float)sm0[e+4] + sn1[e] * (float)sg0[e+4]);\
            w1_[e]   = (__bf16)((float)sm1[e]   + sn2[e] * (float)sg1[e]);  \
            w1_[e+4] = (__bf16)((float)sm1[e+4] + sn3[e] * (float)sg1[e+4]);\
        }                                                                   \
        *(bf16x8*)(smem + (d_) * 16384 + wb)               = a0_;           \
        *(bf16x8*)(smem + (d_) * 16384 + wb + 4096)        = a1_;           \
        *(bf16x8*)(smem + (d_) * 16384 + 8192 + wb)        = w0_;           \
        *(bf16x8*)(smem + (d_) * 16384 + 8192 + wb + 4096) = w1_;           \
    } while (0)

    // ---- frag read byte offsets (linear 64B rows; 2-way quad aliasing = free) ----
    int aoff[4], boff[4];
    #pragma unroll
    for (int f = 0; f < 4; ++f) {
        aoff[f] = (wr * 64 + f * 16 + hr) * 64 + kq * 16;
        boff[f] = 8192 + (wc * 64 + f * 16 + hr) * 64 + kq * 16;
    }

    f32x4 acc[4][4];
    #pragma unroll
    for (int m = 0; m < 4; ++m)
        #pragma unroll
        for (int n = 0; n < 4; ++n)
            acc[m][n] = (f32x4)(0.0f);

    // ---- prologue: build tile 0 into buf 0; issue tile 1 ----
    ISSUE(0);
    TW(0);                  // compiler waits vmcnt for staged regs
    ISSUE(32);
    LGKM0();
    BARRIER();

    for (int t = 0; t < NST; ++t) {
        const char* base = smem + (t & 1) * 16384;

        bf16x8 af[4], bfr[4];
        #pragma unroll
        for (int f = 0; f < 4; ++f) {
            af[f]  = *(const bf16x8*)(base + aoff[f]);
            bfr[f] = *(const bf16x8*)(base + boff[f]);
        }

        __builtin_amdgcn_s_setprio(1);
        #pragma unroll
        for (int m = 0; m < 4; ++m)
            #pragma unroll
            for (int n = 0; n < 4; ++n)
                acc[m][n] = __builtin_amdgcn_mfma_f32_16x16x32_bf16(af[m], bfr[n], acc[m][n], 0, 0, 0);
        __builtin_amdgcn_s_setprio(0);

        if (t + 1 < NST) TW((t + 1) & 1);          // transform tile t+1, write other buf
        if (t + 2 < NST) ISSUE((t + 2) * 32);      // prefetch tile t+2
        LGKM0();                                   // ds_writes visible to all waves
        BARRIER();
    }
#undef ISSUE
#undef TW

    // ---- epilogue: LDS transpose -> coalesced stores (512B contiguous per wave-instr) ----
    {
        float* eb = (float*)smem;                  // [64][130] f32 per round
        const f32x2 bias2 = *(const f32x2*)(bias + nt * 128 + lane * 2);
        float* ob = out + ((size_t)b * L_ + mt * 128) * O_ + nt * 128;
        #pragma unroll
        for (int r = 0; r < 2; ++r) {
            BARRIER();                             // prior LDS use done
            if (wr == r) {
                #pragma unroll
                for (int m = 0; m < 4; ++m)
                    #pragma unroll
                    for (int n = 0; n < 4; ++n) {
                        const int col = wc * 64 + n * 16 + hr;
                        #pragma unroll
                        for (int j = 0; j < 4; ++j)
                            eb[(m * 16 + kq * 4 + j) * 130 + col] = acc[m][n][j];
                    }
            }
            LGKM0();
            BARRIER();                             // publish slab
            #pragma unroll
            for (int rr = 0; rr < 16; ++rr) {
                const int row = wave * 16 + rr;    // 0..63
                f32x2 v = *(const f32x2*)&eb[row * 130 + lane * 2];
                v[0] += bias2[0]; v[1] += bias2[1];
                *(f32x2*)&ob[(size_t)(r * 64 + row) * O_ + lane * 2] = v;
            }
        }
    }
}

// ============================ Fallback (no workspace): R1 fused kernel ============================
#define LDSPAD 40
__global__ void bayes_gemm_fused(const float* __restrict__ x,
                                 const float* __restrict__ wmean,
                                 const float* __restrict__ wlogvar,
                                 const float* __restrict__ bias,
                                 const float* __restrict__ noise,
                                 float* __restrict__ out)
{
    __shared__ __bf16 As[128 * LDSPAD];
    __shared__ __bf16 Bs[128 * LDSPAD];
    const int bid  = blockIdx.x;
    const int b    = bid >> 5;
    const int mt   = (bid >> 3) & 3;
    const int nt   = bid & 7;
    const int t    = threadIdx.x;
    const int wave = t >> 6, lane = t & 63;
    const int wr   = wave >> 1, wc = wave & 1;
    const int hr   = lane & 15, kq = lane >> 4;
    const float* xb = x     + (size_t)b * L_ * I_;
    const float* nb = noise + (size_t)b * O_ * I_;
    f32x4 acc[4][4];
    #pragma unroll
    for (int m = 0; m < 4; ++m)
        #pragma unroll
        for (int n = 0; n < 4; ++n) acc[m][n] = (f32x4)(0.0f);
    for (int k0 = 0; k0 < I_; k0 += 32) {
        #pragma unroll
        for (int j = 0; j < 4; ++j) {
            const int s = t + j * 256, row = s >> 3, q = s & 7;
            const float4 v = *(const float4*)(xb + (size_t)(mt * 128 + row) * I_ + k0 + q * 4);
            __bf16* dst = &As[row * LDSPAD + q * 4];
            dst[0] = (__bf16)v.x; dst[1] = (__bf16)v.y; dst[2] = (__bf16)v.z; dst[3] = (__bf16)v.w;
        }
        #pragma unroll
        for (int j = 0; j < 4; ++j) {
            const int s = t + j * 256, row = s >> 3, q = s & 7;
            const size_t off = (size_t)(nt * 128 + row) * I_ + k0 + q * 4;
            const float4 m4 = *(const float4*)(wmean + off);
            const float4 l4 = *(const float4*)(wlogvar + off);
            const float4 n4 = *(const float4*)(nb + off);
            __bf16* dst = &Bs[row * LDSPAD + q * 4];
            dst[0] = (__bf16)(m4.x + n4.x * __expf(0.5f * l4.x));
            dst[1] = (__bf16)(m4.y + n4.y * __expf(0.5f * l4.y));
            dst[2] = (__bf16)(m4.z + n4.z * __expf(0.5f * l4.z));
            dst[3] = (__bf16)(m4.w + n4.w * __expf(0.5f * l4.w));
        }
        __syncthreads();
        bf16x8 af[4], bfr[4];
        #pragma unroll
        for (int m = 0; m < 4; ++m)
            af[m] = *(const bf16x8*)&As[(wr * 64 + m * 16 + hr) * LDSPAD + kq * 8];
        #pragma unroll
        for (int n = 0; n < 4; ++n)
            bfr[n] = *(const bf16x8*)&Bs[(wc * 64 + n * 16 + hr) * LDSPAD + kq * 8];
        #pragma unroll
        for (int m = 0; m < 4; ++m)
            #pragma unroll
            for (int n = 0; n < 4; ++n)
                acc[m][n] = __builtin_amdgcn_mfma_f32_16x16x32_bf16(af[m], bfr[n], acc[m][n], 0, 0, 0);
        __syncthreads();
    }
    float* ob = out + (size_t)b * L_ * O_;
    #pragma unroll
    for (int n = 0; n < 4; ++n) {
        const int col = nt * 128 + wc * 64 + n * 16 + hr;
        const float bv = bias[col];
        #pragma unroll
        for (int m = 0; m < 4; ++m) {
            const int row0 = mt * 128 + wr * 64 + m * 16 + kq * 4;
            #pragma unroll
            for (int j = 0; j < 4; ++j)
                ob[(size_t)(row0 + j) * O_ + col] = acc[m][n][j] + bv;
        }
    }
}

extern "C" void kernel_launch(void* const* d_in, const int* in_sizes, int n_in,
                              void* d_out, int out_size, void* d_ws, size_t ws_size,
                              hipStream_t stream) {
    const float* x       = (const float*)d_in[0];
    const float* wmean   = (const float*)d_in[1];
    const float* wlogvar = (const float*)d_in[2];
    const float* bias    = (const float*)d_in[3];
    const float* noise   = (const float*)d_in[4];
    float* out           = (float*)d_out;

    const size_t ms_bytes = (size_t)O_ * I_ * 2 * 2;   // mean bf16 + sigma bf16 = 4 MiB

    if (ws_size >= ms_bytes) {
        __bf16* mzb = (__bf16*)d_ws;
        __bf16* sgb = mzb + (size_t)O_ * I_;
        gen_ms_kernel<<<dim3(O_ * I_ / 4 / 256), dim3(256), 0, stream>>>(wmean, wlogvar, mzb, sgb);
        fused_gemm<<<dim3(1024), dim3(256), 0, stream>>>(x, noise, mzb, sgb, bias, out);
    } else {
        bayes_gemm_fused<<<dim3(1024), dim3(256), 0, stream>>>(
            x, wmean, wlogvar, bias, noise, out);
    }
}